// Round 1
// baseline (408.934 us; speedup 1.0000x reference)
//
#include <hip/hip_runtime.h>
#include <hip/hip_bf16.h>

#define B_  8192
#define D_  784
#define H_  2048
#define O_  1024
#define RH_ 128
#define P_  64
#define KP  224   // 196 padded to 7*32

typedef __attribute__((ext_vector_type(8))) short short8;
typedef __attribute__((ext_vector_type(4))) float f32x4;

__device__ inline float bf2f(unsigned short u) {
  union { unsigned int i; float f; } v; v.i = ((unsigned int)u) << 16; return v.f;
}
__device__ inline unsigned short f2bf(float f) {
  __hip_bfloat16 h = __float2bfloat16(f);
  return *reinterpret_cast<unsigned short*>(&h);
}
// Abramowitz-Stegun 7.1.26, max abs err ~1.5e-7 (exact-gelu grade)
__device__ inline float erf_fast(float x) {
  float ax = fabsf(x);
  float t = 1.0f / (1.0f + 0.3275911f * ax);
  float p = ((((1.061405429f * t - 1.453152027f) * t + 1.421413741f) * t
              - 0.284496736f) * t + 0.254829592f) * t;
  float y = 1.0f - p * __expf(-ax * ax);
  return x < 0.f ? -y : y;
}

__device__ inline void gload_lds16(const void* g, void* l) {
  __builtin_amdgcn_global_load_lds((const __attribute__((address_space(1))) void*)g,
                                   (__attribute__((address_space(3))) void*)l, 16, 0, 0);
}

// C = A(128xK) * B(128xK)^T, both K-major bf16 (ushort), K % 32 == 0.
// 4 waves in 2x2, each wave 64x64 (4x4 frags of 16x16x32 MFMA). m97-style.
__device__ inline void gemm128_bt(const unsigned short* __restrict__ A,
                                  const unsigned short* __restrict__ Bm,
                                  int K, unsigned short* smem, f32x4 acc[4][4]) {
  const int t = threadIdx.x;
  const int w = t >> 6, l = t & 63;
  const int wr = (w >> 1) * 64, wc = (w & 1) * 64;
  const size_t srcOff = (size_t)(t >> 2) * K + (t & 3) * 8;
  const unsigned short* gA = A + srcOff;
  const unsigned short* gB = Bm + srcOff;
  char* lds = (char*)smem;
  char* ldsT = lds + t * 16;
  const int lr = l & 15;
  const int lkb = (l >> 4) * 16;              // k byte offset within 64B row
  const int arow = (wr + lr) * 64 + lkb;
  const int brow = 8192 + (wc + lr) * 64 + lkb;
  const size_t halfA = (size_t)64 * K;
  for (int kt = 0; kt < K; kt += 32) {
    gload_lds16(gA + kt,         ldsT);
    gload_lds16(gA + kt + halfA, ldsT + 4096);
    gload_lds16(gB + kt,         ldsT + 8192);
    gload_lds16(gB + kt + halfA, ldsT + 12288);
    __syncthreads();
    short8 af[4], bfr[4];
#pragma unroll
    for (int f = 0; f < 4; ++f) {
      af[f]  = *(const short8*)(lds + arow + f * 1024);
      bfr[f] = *(const short8*)(lds + brow + f * 1024);
    }
#pragma unroll
    for (int fm = 0; fm < 4; ++fm)
#pragma unroll
      for (int fn = 0; fn < 4; ++fn)
        acc[fm][fn] = __builtin_amdgcn_mfma_f32_16x16x32_bf16(af[fm], bfr[fn], acc[fm][fn], 0, 0, 0);
    __syncthreads();
  }
}

// ---- prep: gather/pad/convert x_reg, W1g; convert W2 to bf16 ----
__global__ void k_prep(const float* __restrict__ x, const float* __restrict__ W1,
                       const float* __restrict__ W2, const int* __restrict__ ig,
                       unsigned short* __restrict__ xreg, unsigned short* __restrict__ w1g,
                       unsigned short* __restrict__ w2b) {
  const size_t N1 = (size_t)4 * B_ * KP;
  const size_t N2 = (size_t)4 * H_ * KP;
  const size_t N3 = (size_t)O_ * H_;
  const size_t TOT = N1 + N2 + N3;
  for (size_t idx = (size_t)blockIdx.x * blockDim.x + threadIdx.x; idx < TOT;
       idx += (size_t)gridDim.x * blockDim.x) {
    if (idx < N1) {
      int n = (int)(idx % KP); size_t r = idx / KP;
      int b = (int)(r % B_); int i = (int)(r / B_);
      float v = (n < 196) ? x[(size_t)b * D_ + ig[i * 196 + n]] : 0.f;
      xreg[idx] = f2bf(v);
    } else if (idx < N1 + N2) {
      size_t q = idx - N1;
      int n = (int)(q % KP); size_t r = q / KP;
      int h = (int)(r % H_); int i = (int)(r / H_);
      float v = (n < 196) ? W1[(size_t)h * D_ + ig[i * 196 + n]] : 0.f;
      w1g[q] = f2bf(v);
    } else {
      size_t q = idx - N1 - N2;
      w2b[q] = f2bf(W2[q]);
    }
  }
}

// ---- router: fp32 (selection-critical), 16 samples/block ----
#define RBS 16
__global__ __launch_bounds__(256) void k_router(const float* __restrict__ x,
    const float* __restrict__ Wr1, const float* __restrict__ br1,
    const float* __restrict__ Wr2, const float* __restrict__ br2,
    float* __restrict__ wts, float* __restrict__ wsum) {
  __shared__ float xs[RBS][788];   // pad 784->788: conflict-free
  __shared__ float hr[RBS][132];
  __shared__ float sc[RBS][66];
  const int b0 = blockIdx.x * RBS;
  const int t = threadIdx.x;
  for (int idx = t; idx < RBS * 196; idx += 256) {
    int s = idx / 196, v = idx - s * 196;
    *(float4*)&xs[s][v * 4] = *(const float4*)(x + (size_t)(b0 + s) * D_ + v * 4);
  }
  __syncthreads();
  const int s = t & 15;
  const int lane_h = t >> 4;
  for (int h = lane_h; h < RH_; h += 16) {
    const float4* wr = (const float4*)(Wr1 + (size_t)h * D_);
    float acc = 0.f;
    for (int v = 0; v < 196; ++v) {
      float4 wv = wr[v];
      float4 xv = *(const float4*)&xs[s][v * 4];
      acc += wv.x * xv.x + wv.y * xv.y + wv.z * xv.z + wv.w * xv.w;
    }
    acc += br1[h];
    hr[s][h] = fmaxf(acc, 0.f);
  }
  __syncthreads();
  for (int p = lane_h; p < P_; p += 16) {
    const float4* wr = (const float4*)(Wr2 + (size_t)p * RH_);
    float acc = 0.f;
#pragma unroll
    for (int v = 0; v < 32; ++v) {
      float4 wv = wr[v];
      float4 hv = *(const float4*)&hr[s][v * 4];
      acc += wv.x * hv.x + wv.y * hv.y + wv.z * hv.z + wv.w * hv.w;
    }
    sc[s][p] = acc + br2[p];
  }
  __syncthreads();
  if (t < RBS) {
    float m = -1e30f;
    for (int p = 0; p < P_; ++p) m = fmaxf(m, sc[t][p]);
    float Z = 0.f;
    for (int p = 0; p < P_; ++p) { float e = __expf(sc[t][p] - m); sc[t][p] = e; Z += e; }
    unsigned long long used = 0ULL;
    float ssum = 0.f;
    for (int it = 0; it < 8; ++it) {          // top-8, first-index tie-break (matches lax.top_k)
      int best = 0; float bv = -1.f;
      for (int p = 0; p < P_; ++p)
        if (!((used >> p) & 1ULL) && sc[t][p] > bv) { bv = sc[t][p]; best = p; }
      used |= 1ULL << best;
      ssum += bv;
    }
    // wts_p = (e_p/Z)/(ssum/Z + 1e-8) = e_p/(ssum + 1e-8*Z)
    const float dn = 1.0f / (ssum + 1e-8f * Z);
    float* wrow = wts + (size_t)(b0 + t) * 64;
    float ks[4] = {0.f, 0.f, 0.f, 0.f};
    for (int p = 0; p < P_; ++p) {
      float wv = ((used >> p) & 1ULL) ? sc[t][p] * dn : 0.f;
      wrow[p] = wv;
      ks[p & 3] += wv;                         // p = i*16+j*4+k -> k = p&3
    }
    float* wsr = wsum + (size_t)(b0 + t) * 4;
    for (int k = 0; k < 4; ++k) wsr[k] = ks[k];
  }
}

// ---- layer 1: hidden[i][b][n] = gelu(xreg_i @ w1g_i^T + b1) ----
__global__ __launch_bounds__(256) void k_l1(const unsigned short* __restrict__ xreg,
    const unsigned short* __restrict__ w1g, const float* __restrict__ b1,
    unsigned short* __restrict__ hidden) {
  __shared__ __align__(128) unsigned short smem[8192];
  const int mt = blockIdx.x, nt = blockIdx.y, iq = blockIdx.z;
  const unsigned short* A  = xreg + ((size_t)iq * B_ + mt * 128) * KP;
  const unsigned short* Bm = w1g + ((size_t)iq * H_ + nt * 128) * KP;
  f32x4 acc[4][4];
#pragma unroll
  for (int a = 0; a < 4; ++a)
#pragma unroll
    for (int b = 0; b < 4; ++b) acc[a][b] = (f32x4){0.f, 0.f, 0.f, 0.f};
  gemm128_bt(A, Bm, KP, smem, acc);
  const int t = threadIdx.x, w = t >> 6, l = t & 63;
  const int rbase = mt * 128 + (w >> 1) * 64 + (l >> 4) * 4;
  const int cbase = nt * 128 + (w & 1) * 64 + (l & 15);
#pragma unroll
  for (int fn = 0; fn < 4; ++fn) {
    const int n = cbase + fn * 16;
    const float bias = b1[n];
#pragma unroll
    for (int fm = 0; fm < 4; ++fm)
#pragma unroll
      for (int r = 0; r < 4; ++r) {
        const int m = rbase + fm * 16 + r;
        float v = acc[fm][fn][r] + bias;
        float g = 0.5f * v * (1.0f + erf_fast(v * 0.70710678118654752f));
        hidden[((size_t)iq * B_ + m) * H_ + n] = f2bf(g);
      }
  }
}

// ---- combine (in-place i->k): G[k][b][n] = sum_i hidden[i][b][n]*wts[b][i*16+j*4+k] ----
__global__ __launch_bounds__(256) void k_combine(unsigned short* __restrict__ hid,
                                                 const float* __restrict__ wts) {
  const int b = blockIdx.x;
  const int n = threadIdx.x * 8;
  const int j = n >> 9;
  const float* wb = wts + (size_t)b * 64;
  float hv[4][8];
#pragma unroll
  for (int i = 0; i < 4; ++i) {
    short8 raw = *(const short8*)(hid + ((size_t)i * B_ + b) * H_ + n);
#pragma unroll
    for (int e = 0; e < 8; ++e) hv[i][e] = bf2f((unsigned short)raw[e]);
  }
  short8 outv[4];
#pragma unroll
  for (int k = 0; k < 4; ++k) {
    const float w0 = wb[0 + j * 4 + k], w1 = wb[16 + j * 4 + k];
    const float w2 = wb[32 + j * 4 + k], w3 = wb[48 + j * 4 + k];
#pragma unroll
    for (int e = 0; e < 8; ++e) {
      float sv = hv[0][e] * w0 + hv[1][e] * w1 + hv[2][e] * w2 + hv[3][e] * w3;
      outv[k][e] = (short)f2bf(sv);
    }
  }
#pragma unroll
  for (int k = 0; k < 4; ++k)
    *(short8*)(hid + ((size_t)k * B_ + b) * H_ + n) = outv[k];
}

// ---- layer 2: out[b][k*256+o] = G_k @ W2_k^T + wsum[b][k]*b2 ----
__global__ __launch_bounds__(256) void k_l2(const unsigned short* __restrict__ G,
    const unsigned short* __restrict__ w2b, const float* __restrict__ b2,
    const float* __restrict__ wsum, float* __restrict__ out) {
  __shared__ __align__(128) unsigned short smem[8192];
  const int mt = blockIdx.x, nt = blockIdx.y, k = blockIdx.z;
  const unsigned short* A  = G + ((size_t)k * B_ + mt * 128) * H_;
  const unsigned short* Bm = w2b + ((size_t)(k * 256 + nt * 128)) * H_;
  f32x4 acc[4][4];
#pragma unroll
  for (int a = 0; a < 4; ++a)
#pragma unroll
    for (int b = 0; b < 4; ++b) acc[a][b] = (f32x4){0.f, 0.f, 0.f, 0.f};
  gemm128_bt(A, Bm, H_, smem, acc);
  const int t = threadIdx.x, w = t >> 6, l = t & 63;
  const int rbase = mt * 128 + (w >> 1) * 64 + (l >> 4) * 4;
  const int cb = nt * 128 + (w & 1) * 64 + (l & 15);
#pragma unroll
  for (int fn = 0; fn < 4; ++fn) {
    const int ncol = k * 256 + cb + fn * 16;
    const float bias = b2[ncol];
#pragma unroll
    for (int fm = 0; fm < 4; ++fm)
#pragma unroll
      for (int r = 0; r < 4; ++r) {
        const int m = rbase + fm * 16 + r;
        out[(size_t)m * O_ + ncol] = acc[fm][fn][r] + wsum[m * 4 + k] * bias;
      }
  }
}

extern "C" void kernel_launch(void* const* d_in, const int* in_sizes, int n_in,
                              void* d_out, int out_size, void* d_ws, size_t ws_size,
                              hipStream_t stream) {
  const float* x   = (const float*)d_in[0];
  const float* W1  = (const float*)d_in[1];
  const float* b1  = (const float*)d_in[2];
  const float* W2  = (const float*)d_in[3];
  const float* b2  = (const float*)d_in[4];
  const float* Wr1 = (const float*)d_in[5];
  const float* br1 = (const float*)d_in[6];
  const float* Wr2 = (const float*)d_in[7];
  const float* br2 = (const float*)d_in[8];
  const int*   ig  = (const int*)d_in[9];
  float* out = (float*)d_out;
  char* ws = (char*)d_ws;
  // ws layout (bytes):
  unsigned short* xreg = (unsigned short*)(ws);              // 4*8192*224*2 = 14,680,064
  unsigned short* w1g  = (unsigned short*)(ws + 14680064);   // 4*2048*224*2 =  3,670,016
  unsigned short* w2b  = (unsigned short*)(ws + 18350080);   // 1024*2048*2  =  4,194,304
  float*          wts  = (float*)(ws + 22544384);            // 8192*64*4    =  2,097,152
  float*          wsum = (float*)(ws + 24641536);            // 8192*4*4     =    131,072
  unsigned short* hid  = (unsigned short*)(ws + 24772608);   // 4*8192*2048*2 = 134,217,728 (total ~159MB)

  k_prep<<<dim3(2048), dim3(256), 0, stream>>>(x, W1, W2, ig, xreg, w1g, w2b);
  k_router<<<dim3(B_ / RBS), dim3(256), 0, stream>>>(x, Wr1, br1, Wr2, br2, wts, wsum);
  k_l1<<<dim3(B_ / 128, H_ / 128, 4), dim3(256), 0, stream>>>(xreg, w1g, b1, hid);
  k_combine<<<dim3(B_), dim3(256), 0, stream>>>(hid, wts);
  k_l2<<<dim3(B_ / 128, 2, 4), dim3(256), 0, stream>>>(hid, w2b, b2, wsum, out);
}

// Round 2
// 273.482 us; speedup vs baseline: 1.4953x; 1.4953x over previous
//
#include <hip/hip_runtime.h>
#include <hip/hip_bf16.h>

#define B_  8192
#define D_  784
#define H_  2048
#define O_  1024
#define RH_ 128
#define P_  64
#define KP  224   // 196 padded to 7*32

typedef __attribute__((ext_vector_type(8))) short short8;
typedef __attribute__((ext_vector_type(4))) float f32x4;

__device__ inline float bf2f(unsigned short u) {
  union { unsigned int i; float f; } v; v.i = ((unsigned int)u) << 16; return v.f;
}
__device__ inline unsigned short f2bf(float f) {
  __hip_bfloat16 h = __float2bfloat16(f);
  return *reinterpret_cast<unsigned short*>(&h);
}
// Abramowitz-Stegun 7.1.26, max abs err ~1.5e-7 (exact-gelu grade)
__device__ inline float erf_fast(float x) {
  float ax = fabsf(x);
  float t = 1.0f / (1.0f + 0.3275911f * ax);
  float p = ((((1.061405429f * t - 1.453152027f) * t + 1.421413741f) * t
              - 0.284496736f) * t + 0.254829592f) * t;
  float y = 1.0f - p * __expf(-ax * ax);
  return x < 0.f ? -y : y;
}

__device__ inline void gload_lds16(const void* g, void* l) {
  __builtin_amdgcn_global_load_lds((const __attribute__((address_space(1))) void*)g,
                                   (__attribute__((address_space(3))) void*)l, 16, 0, 0);
}

// C = A(128xK) * B(128xK)^T, both K-major bf16 (ushort), K % 32 == 0.
__device__ inline void gemm128_bt(const unsigned short* __restrict__ A,
                                  const unsigned short* __restrict__ Bm,
                                  int K, unsigned short* smem, f32x4 acc[4][4]) {
  const int t = threadIdx.x;
  const int w = t >> 6, l = t & 63;
  const int wr = (w >> 1) * 64, wc = (w & 1) * 64;
  const size_t srcOff = (size_t)(t >> 2) * K + (t & 3) * 8;
  const unsigned short* gA = A + srcOff;
  const unsigned short* gB = Bm + srcOff;
  char* lds = (char*)smem;
  char* ldsT = lds + t * 16;
  const int lr = l & 15;
  const int lkb = (l >> 4) * 16;
  const int arow = (wr + lr) * 64 + lkb;
  const int brow = 8192 + (wc + lr) * 64 + lkb;
  const size_t halfA = (size_t)64 * K;
  for (int kt = 0; kt < K; kt += 32) {
    gload_lds16(gA + kt,         ldsT);
    gload_lds16(gA + kt + halfA, ldsT + 4096);
    gload_lds16(gB + kt,         ldsT + 8192);
    gload_lds16(gB + kt + halfA, ldsT + 12288);
    __syncthreads();
    short8 af[4], bfr[4];
#pragma unroll
    for (int f = 0; f < 4; ++f) {
      af[f]  = *(const short8*)(lds + arow + f * 1024);
      bfr[f] = *(const short8*)(lds + brow + f * 1024);
    }
#pragma unroll
    for (int fm = 0; fm < 4; ++fm)
#pragma unroll
      for (int fn = 0; fn < 4; ++fn)
        acc[fm][fn] = __builtin_amdgcn_mfma_f32_16x16x32_bf16(af[fm], bfr[fn], acc[fm][fn], 0, 0, 0);
    __syncthreads();
  }
}

// ---- prep: gather/pad/convert x_reg, W1g; convert W2 to bf16 ----
__global__ void k_prep(const float* __restrict__ x, const float* __restrict__ W1,
                       const float* __restrict__ W2, const int* __restrict__ ig,
                       unsigned short* __restrict__ xreg, unsigned short* __restrict__ w1g,
                       unsigned short* __restrict__ w2b) {
  const size_t N1 = (size_t)4 * B_ * KP;
  const size_t N2 = (size_t)4 * H_ * KP;
  const size_t N3 = (size_t)O_ * H_;
  const size_t TOT = N1 + N2 + N3;
  for (size_t idx = (size_t)blockIdx.x * blockDim.x + threadIdx.x; idx < TOT;
       idx += (size_t)gridDim.x * blockDim.x) {
    if (idx < N1) {
      int n = (int)(idx % KP); size_t r = idx / KP;
      int b = (int)(r % B_); int i = (int)(r / B_);
      float v = (n < 196) ? x[(size_t)b * D_ + ig[i * 196 + n]] : 0.f;
      xreg[idx] = f2bf(v);
    } else if (idx < N1 + N2) {
      size_t q = idx - N1;
      int n = (int)(q % KP); size_t r = q / KP;
      int h = (int)(r % H_); int i = (int)(r / H_);
      float v = (n < 196) ? W1[(size_t)h * D_ + ig[i * 196 + n]] : 0.f;
      w1g[q] = f2bf(v);
    } else {
      size_t q = idx - N1 - N2;
      w2b[q] = f2bf(W2[q]);
    }
  }
}

// ---- router stage 1: h_r = relu(x @ Wr1^T + br1), fp32 register-blocked GEMM ----
// grid (B/64, RH/64); block 256; each thread 4x4 outputs; K-tile 32.
__global__ __launch_bounds__(256) void k_r1(const float* __restrict__ x,
    const float* __restrict__ Wr1, const float* __restrict__ br1,
    float* __restrict__ hr) {
  __shared__ float As[64][33];
  __shared__ float Bs[64][33];
  const int b0 = blockIdx.x * 64;
  const int h0 = blockIdx.y * 64;
  const int t = threadIdx.x;
  const int srow = t >> 2;            // staging row 0..63
  const int scol = (t & 3) * 8;       // staging col 0,8,16,24
  const int ty = t >> 4, tx = t & 15;
  float acc[4][4];
#pragma unroll
  for (int i = 0; i < 4; ++i)
#pragma unroll
    for (int j = 0; j < 4; ++j) acc[i][j] = 0.f;
  const float* gA = x   + (size_t)(b0 + srow) * D_;
  const float* gB = Wr1 + (size_t)(h0 + srow) * D_;
  for (int k0 = 0; k0 < D_; k0 += 32) {
    // stage A (x tile) and B (Wr1 tile), zero-pad past 784
    float4 a0 = (k0 + scol     < D_) ? *(const float4*)(gA + k0 + scol)     : float4{0,0,0,0};
    float4 a1 = (k0 + scol + 4 < D_) ? *(const float4*)(gA + k0 + scol + 4) : float4{0,0,0,0};
    float4 w0 = (k0 + scol     < D_) ? *(const float4*)(gB + k0 + scol)     : float4{0,0,0,0};
    float4 w1 = (k0 + scol + 4 < D_) ? *(const float4*)(gB + k0 + scol + 4) : float4{0,0,0,0};
    __syncthreads();   // protect previous tile's readers before overwrite
    *(float4*)&As[srow][scol]     = a0;
    *(float4*)&As[srow][scol + 4] = a1;
    *(float4*)&Bs[srow][scol]     = w0;
    *(float4*)&Bs[srow][scol + 4] = w1;
    __syncthreads();
#pragma unroll
    for (int kk = 0; kk < 8; ++kk) {
      float4 a4[4], b4[4];
#pragma unroll
      for (int i = 0; i < 4; ++i) a4[i] = *(const float4*)&As[ty * 4 + i][kk * 4];
#pragma unroll
      for (int j = 0; j < 4; ++j) b4[j] = *(const float4*)&Bs[tx * 4 + j][kk * 4];
#pragma unroll
      for (int i = 0; i < 4; ++i)
#pragma unroll
        for (int j = 0; j < 4; ++j)
          acc[i][j] += a4[i].x * b4[j].x + a4[i].y * b4[j].y +
                       a4[i].z * b4[j].z + a4[i].w * b4[j].w;
    }
  }
#pragma unroll
  for (int j = 0; j < 4; ++j) {
    const int h = h0 + tx * 4 + j;
    const float bias = br1[h];
#pragma unroll
    for (int i = 0; i < 4; ++i)
      hr[(size_t)(b0 + ty * 4 + i) * RH_ + h] = fmaxf(acc[i][j] + bias, 0.f);
  }
}

// ---- router stage 2: scores -> softmax -> top-8 -> weights. One wave per sample. ----
#define R2S 32   // samples per block
__global__ __launch_bounds__(256) void k_r2(const float* __restrict__ hr,
    const float* __restrict__ Wr2, const float* __restrict__ br2,
    float* __restrict__ wts, float* __restrict__ wsum) {
  __shared__ float Ws[64][130];
  __shared__ float hs[R2S][128];
  const int s0 = blockIdx.x * R2S;
  const int t = threadIdx.x;
  // stage Wr2 (64x128)
  for (int idx = t; idx < 2048; idx += 256) {
    int r = idx >> 5, c = (idx & 31) * 4;
    *(float4*)&Ws[r][c] = *(const float4*)(Wr2 + (size_t)r * RH_ + c);
  }
  // stage h_r rows
  for (int idx = t; idx < R2S * 32; idx += 256) {
    int r = idx >> 5, c = (idx & 31) * 4;
    *(float4*)&hs[r][c] = *(const float4*)(hr + (size_t)(s0 + r) * RH_ + c);
  }
  __syncthreads();
  const int w = t >> 6, p = t & 63;
  const float wb2 = br2[p];
  for (int si = 0; si < R2S / 4; ++si) {
    const int sl = w * (R2S / 4) + si;     // local sample
    float sc = wb2;
#pragma unroll
    for (int kk = 0; kk < 32; ++kk) {
      float4 h4 = *(const float4*)&hs[sl][kk * 4];
      float4 w4 = *(const float4*)&Ws[p][kk * 4];
      sc += h4.x * w4.x + h4.y * w4.y + h4.z * w4.z + h4.w * w4.w;
    }
    // softmax (lane p holds score p)
    float m = sc;
#pragma unroll
    for (int o = 32; o; o >>= 1) m = fmaxf(m, __shfl_xor(m, o));
    float e = __expf(sc - m);
    float Z = e;
#pragma unroll
    for (int o = 32; o; o >>= 1) Z += __shfl_xor(Z, o);
    // top-8 with lowest-index tie-break (matches lax.top_k)
    bool sel = false;
    float ssum = 0.f;
    for (int it = 0; it < 8; ++it) {
      float v = sel ? -1.f : e;
      float vm = v;
#pragma unroll
      for (int o = 32; o; o >>= 1) vm = fmaxf(vm, __shfl_xor(vm, o));
      unsigned long long mask = __ballot(!sel && v == vm);
      int first = __ffsll((long long)mask) - 1;
      if (p == first) sel = true;
      ssum += vm;
    }
    const float dn = 1.0f / (ssum + 1e-8f * Z);
    const float wv = sel ? e * dn : 0.f;
    wts[(size_t)(s0 + sl) * 64 + p] = wv;
    // per-k sums: k = p & 3
    float part = wv;
#pragma unroll
    for (int o = 4; o < 64; o <<= 1) part += __shfl_xor(part, o);
    if (p < 4) wsum[(size_t)(s0 + sl) * 4 + p] = part;
  }
}

// ---- layer 1: hidden[i][b][n] = gelu(xreg_i @ w1g_i^T + b1) ----
__global__ __launch_bounds__(256) void k_l1(const unsigned short* __restrict__ xreg,
    const unsigned short* __restrict__ w1g, const float* __restrict__ b1,
    unsigned short* __restrict__ hidden) {
  __shared__ __align__(128) unsigned short smem[8192];
  const int mt = blockIdx.x, nt = blockIdx.y, iq = blockIdx.z;
  const unsigned short* A  = xreg + ((size_t)iq * B_ + mt * 128) * KP;
  const unsigned short* Bm = w1g + ((size_t)iq * H_ + nt * 128) * KP;
  f32x4 acc[4][4];
#pragma unroll
  for (int a = 0; a < 4; ++a)
#pragma unroll
    for (int b = 0; b < 4; ++b) acc[a][b] = (f32x4){0.f, 0.f, 0.f, 0.f};
  gemm128_bt(A, Bm, KP, smem, acc);
  const int t = threadIdx.x, w = t >> 6, l = t & 63;
  const int rbase = mt * 128 + (w >> 1) * 64 + (l >> 4) * 4;
  const int cbase = nt * 128 + (w & 1) * 64 + (l & 15);
#pragma unroll
  for (int fn = 0; fn < 4; ++fn) {
    const int n = cbase + fn * 16;
    const float bias = b1[n];
#pragma unroll
    for (int fm = 0; fm < 4; ++fm)
#pragma unroll
      for (int r = 0; r < 4; ++r) {
        const int m = rbase + fm * 16 + r;
        float v = acc[fm][fn][r] + bias;
        float g = 0.5f * v * (1.0f + erf_fast(v * 0.70710678118654752f));
        hidden[((size_t)iq * B_ + m) * H_ + n] = f2bf(g);
      }
  }
}

// ---- combine (in-place i->k): G[k][b][n] = sum_i hidden[i][b][n]*wts[b][i*16+j*4+k] ----
__global__ __launch_bounds__(256) void k_combine(unsigned short* __restrict__ hid,
                                                 const float* __restrict__ wts) {
  const int b = blockIdx.x;
  const int n = threadIdx.x * 8;
  const int j = n >> 9;
  const float* wb = wts + (size_t)b * 64;
  float hv[4][8];
#pragma unroll
  for (int i = 0; i < 4; ++i) {
    short8 raw = *(const short8*)(hid + ((size_t)i * B_ + b) * H_ + n);
#pragma unroll
    for (int e = 0; e < 8; ++e) hv[i][e] = bf2f((unsigned short)raw[e]);
  }
  short8 outv[4];
#pragma unroll
  for (int k = 0; k < 4; ++k) {
    const float w0 = wb[0 + j * 4 + k], w1 = wb[16 + j * 4 + k];
    const float w2 = wb[32 + j * 4 + k], w3 = wb[48 + j * 4 + k];
#pragma unroll
    for (int e = 0; e < 8; ++e) {
      float sv = hv[0][e] * w0 + hv[1][e] * w1 + hv[2][e] * w2 + hv[3][e] * w3;
      outv[k][e] = (short)f2bf(sv);
    }
  }
#pragma unroll
  for (int k = 0; k < 4; ++k)
    *(short8*)(hid + ((size_t)k * B_ + b) * H_ + n) = outv[k];
}

// ---- layer 2: out[b][k*256+o] = G_k @ W2_k^T + wsum[b][k]*b2 ----
__global__ __launch_bounds__(256) void k_l2(const unsigned short* __restrict__ G,
    const unsigned short* __restrict__ w2b, const float* __restrict__ b2,
    const float* __restrict__ wsum, float* __restrict__ out) {
  __shared__ __align__(128) unsigned short smem[8192];
  const int mt = blockIdx.x, nt = blockIdx.y, k = blockIdx.z;
  const unsigned short* A  = G + ((size_t)k * B_ + mt * 128) * H_;
  const unsigned short* Bm = w2b + ((size_t)(k * 256 + nt * 128)) * H_;
  f32x4 acc[4][4];
#pragma unroll
  for (int a = 0; a < 4; ++a)
#pragma unroll
    for (int b = 0; b < 4; ++b) acc[a][b] = (f32x4){0.f, 0.f, 0.f, 0.f};
  gemm128_bt(A, Bm, H_, smem, acc);
  const int t = threadIdx.x, w = t >> 6, l = t & 63;
  const int rbase = mt * 128 + (w >> 1) * 64 + (l >> 4) * 4;
  const int cb = nt * 128 + (w & 1) * 64 + (l & 15);
#pragma unroll
  for (int fn = 0; fn < 4; ++fn) {
    const int ncol = k * 256 + cb + fn * 16;
    const float bias = b2[ncol];
#pragma unroll
    for (int fm = 0; fm < 4; ++fm)
#pragma unroll
      for (int r = 0; r < 4; ++r) {
        const int m = rbase + fm * 16 + r;
        out[(size_t)m * O_ + ncol] = acc[fm][fn][r] + wsum[m * 4 + k] * bias;
      }
  }
}

extern "C" void kernel_launch(void* const* d_in, const int* in_sizes, int n_in,
                              void* d_out, int out_size, void* d_ws, size_t ws_size,
                              hipStream_t stream) {
  const float* x   = (const float*)d_in[0];
  const float* W1  = (const float*)d_in[1];
  const float* b1  = (const float*)d_in[2];
  const float* W2  = (const float*)d_in[3];
  const float* b2  = (const float*)d_in[4];
  const float* Wr1 = (const float*)d_in[5];
  const float* br1 = (const float*)d_in[6];
  const float* Wr2 = (const float*)d_in[7];
  const float* br2 = (const float*)d_in[8];
  const int*   ig  = (const int*)d_in[9];
  float* out = (float*)d_out;
  char* ws = (char*)d_ws;
  // ws layout (bytes):
  unsigned short* xreg = (unsigned short*)(ws);              // 4*8192*224*2 = 14,680,064
  unsigned short* w1g  = (unsigned short*)(ws + 14680064);   // 4*2048*224*2 =  3,670,016
  unsigned short* w2b  = (unsigned short*)(ws + 18350080);   // 1024*2048*2  =  4,194,304
  float*          wts  = (float*)(ws + 22544384);            // 8192*64*4    =  2,097,152
  float*          wsum = (float*)(ws + 24641536);            // 8192*4*4     =    131,072
  unsigned short* hid  = (unsigned short*)(ws + 24772608);   // 4*8192*2048*2 = 134,217,728
  float*          hr   = (float*)(ws + 24772608);            // 8192*128*4 = 4MB, aliases hid
                                                             // (dead before k_l1 writes hid)

  k_prep<<<dim3(2048), dim3(256), 0, stream>>>(x, W1, W2, ig, xreg, w1g, w2b);
  k_r1<<<dim3(B_ / 64, RH_ / 64), dim3(256), 0, stream>>>(x, Wr1, br1, hr);
  k_r2<<<dim3(B_ / R2S), dim3(256), 0, stream>>>(hr, Wr2, br2, wts, wsum);
  k_l1<<<dim3(B_ / 128, H_ / 128, 4), dim3(256), 0, stream>>>(xreg, w1g, b1, hid);
  k_combine<<<dim3(B_), dim3(256), 0, stream>>>(hid, wts);
  k_l2<<<dim3(B_ / 128, 2, 4), dim3(256), 0, stream>>>(hid, w2b, b2, wsum, out);
}